// Round 1
// baseline (420.659 us; speedup 1.0000x reference)
//
#include <hip/hip_runtime.h>
#include <math.h>

#define BATCH 64
#define TOK   784        // 785 - 1 local tokens
#define DIM   768
#define FH    28         // int(sqrt(785))
#define IMG   448
#define TOPK  8
#define PE    16

// ---------------------------------------------------------------------------
// Kernel 1: cosine distances. One wave (64 lanes) per (batch, token).
// grid = (196, 64), block = 256 (4 waves). 196*4 = 784 tokens.
// ---------------------------------------------------------------------------
__global__ __launch_bounds__(256) void dist_kernel(const float* __restrict__ x,
                                                   float* __restrict__ dist) {
    const int b    = blockIdx.y;
    const int wave = threadIdx.x >> 6;
    const int lane = threadIdx.x & 63;
    const int t    = blockIdx.x * 4 + wave;   // 0..783

    const float4* g = (const float4*)(x + (size_t)b * 785 * DIM);
    const float4* l = (const float4*)(x + (size_t)b * 785 * DIM + (size_t)(1 + t) * DIM);

    float dot = 0.f, l2 = 0.f, g2 = 0.f;
#pragma unroll
    for (int k = 0; k < 3; ++k) {
        float4 gv = g[lane + 64 * k];
        float4 lv = l[lane + 64 * k];
        dot += gv.x * lv.x + gv.y * lv.y + gv.z * lv.z + gv.w * lv.w;
        l2  += lv.x * lv.x + lv.y * lv.y + lv.z * lv.z + lv.w * lv.w;
        g2  += gv.x * gv.x + gv.y * gv.y + gv.z * gv.z + gv.w * gv.w;
    }
#pragma unroll
    for (int off = 32; off > 0; off >>= 1) {
        dot += __shfl_xor(dot, off);
        l2  += __shfl_xor(l2, off);
        g2  += __shfl_xor(g2, off);
    }
    if (lane == 0) {
        float gn = fmaxf(sqrtf(g2), 1e-8f);
        float ln = fmaxf(sqrtf(l2), 1e-8f);
        dist[b * TOK + t] = dot / (gn * ln);
    }
}

// ---------------------------------------------------------------------------
// Kernel 2: top-8 (iterative argmax, lower-index tie-break = lax.top_k) + box.
// grid = 64, block = 256.
// ---------------------------------------------------------------------------
__global__ __launch_bounds__(256) void topk_kernel(const float* __restrict__ dist,
                                                   int4* __restrict__ boxes) {
    const int b   = blockIdx.x;
    const int tid = threadIdx.x;
    __shared__ float sd[TOK];
    __shared__ float rv[256];
    __shared__ int   ri[256];
    __shared__ int sel_minx, sel_maxx, sel_miny, sel_maxy;

    for (int i = tid; i < TOK; i += 256) sd[i] = dist[b * TOK + i];
    if (tid == 0) { sel_minx = 1 << 30; sel_maxx = -1; sel_miny = 1 << 30; sel_maxy = -1; }
    __syncthreads();

    for (int iter = 0; iter < TOPK; ++iter) {
        float best = -INFINITY;
        int   bi   = TOK;
        for (int i = tid; i < TOK; i += 256) {
            float v = sd[i];
            if (v > best || (v == best && i < bi)) { best = v; bi = i; }
        }
        rv[tid] = best;
        ri[tid] = bi;
        __syncthreads();
        for (int s = 128; s > 0; s >>= 1) {
            if (tid < s) {
                float v2 = rv[tid + s];
                int   i2 = ri[tid + s];
                if (v2 > rv[tid] || (v2 == rv[tid] && i2 < ri[tid])) {
                    rv[tid] = v2;
                    ri[tid] = i2;
                }
            }
            __syncthreads();
        }
        if (tid == 0) {
            int idx = ri[0];
            sd[idx] = -INFINITY;
            int ix = idx / FH, iy = idx % FH;
            sel_minx = min(sel_minx, ix); sel_maxx = max(sel_maxx, ix);
            sel_miny = min(sel_miny, iy); sel_maxy = max(sel_maxy, iy);
        }
        __syncthreads();
    }

    if (tid == 0) {
        int x_i = sel_minx * PE, x_f = sel_maxx * PE;
        int y_i = sel_miny * PE, y_f = sel_maxy * PE;
        int x0 = max(x_i, 0);
        int y0 = max(y_i, 0);
        int x1 = min(max(x_f, x_i + PE), IMG);
        int y1 = min(max(y_f, y_i + PE), IMG);
        boxes[b] = make_int4(x0, x1, y0, y1);
    }
}

// ---------------------------------------------------------------------------
// Kernel 3: bilinear crop-resize (align_corners=True).
// grid = (196, 3, 64), block = 256; each thread = 4 consecutive out pixels.
// 448 % 4 == 0 so a thread never crosses a row boundary.
// ---------------------------------------------------------------------------
__global__ __launch_bounds__(256) void resize_kernel(const float* __restrict__ images,
                                                     const int4* __restrict__ boxes,
                                                     float* __restrict__ out) {
    const int b = blockIdx.z;
    const int c = blockIdx.y;
    const int pix = (blockIdx.x * 256 + threadIdx.x) * 4;  // within 448*448 plane
    const int i = pix / IMG;
    const int j = pix % IMG;

    const int4 box = boxes[b];
    const float x0 = (float)box.x;
    const int   x1 = box.y;
    const float y0 = (float)box.z;
    const int   y1 = box.w;
    const float h = (float)(x1 - box.x);
    const float w = (float)(y1 - box.z);
    const float scale = 1.0f / (float)(IMG - 1);

    // row (first spatial dim) sample coordinate — matches ref: sy = x0 + t*(h-1)*scale
    float sy = x0 + ((float)i * (h - 1.0f)) * scale;
    int   y_lo = (int)floorf(sy);
    int   y_hi = min(y_lo + 1, x1 - 1);
    float wy   = sy - (float)y_lo;

    const float* img = images + ((size_t)b * 3 + c) * (IMG * IMG);
    const float* rlo = img + y_lo * IMG;
    const float* rhi = img + y_hi * IMG;

    float res[4];
#pragma unroll
    for (int k = 0; k < 4; ++k) {
        float sx = y0 + ((float)(j + k) * (w - 1.0f)) * scale;
        int   x_lo = (int)floorf(sx);
        int   x_hi = min(x_lo + 1, y1 - 1);
        float wx   = sx - (float)x_lo;
        float a  = rlo[x_lo];
        float bb = rlo[x_hi];
        float cc = rhi[x_lo];
        float dd = rhi[x_hi];
        res[k] = (1.f - wy) * ((1.f - wx) * a + wx * bb) +
                 wy * ((1.f - wx) * cc + wx * dd);
    }
    float4 o = make_float4(res[0], res[1], res[2], res[3]);
    *(float4*)(out + ((size_t)b * 3 + c) * (IMG * IMG) + pix) = o;
}

// ---------------------------------------------------------------------------
extern "C" void kernel_launch(void* const* d_in, const int* in_sizes, int n_in,
                              void* d_out, int out_size, void* d_ws, size_t ws_size,
                              hipStream_t stream) {
    const float* x      = (const float*)d_in[0];
    const float* images = (const float*)d_in[1];
    float*       out    = (float*)d_out;

    float* dist  = (float*)d_ws;                                  // 64*784 floats
    int4*  boxes = (int4*)((char*)d_ws + BATCH * TOK * sizeof(float)); // 16B-aligned (200704 % 16 == 0)

    dist_kernel<<<dim3(TOK / 4, BATCH), 256, 0, stream>>>(x, dist);
    topk_kernel<<<BATCH, 256, 0, stream>>>(dist, boxes);
    resize_kernel<<<dim3(IMG * IMG / 1024, 3, BATCH), 256, 0, stream>>>(images, boxes, out);
}

// Round 2
// 355.108 us; speedup vs baseline: 1.1846x; 1.1846x over previous
//
#include <hip/hip_runtime.h>
#include <math.h>

#define BATCH 64
#define TOK   784        // 785 - 1 local tokens
#define DIM   768
#define FH    28         // int(sqrt(785))
#define IMG   448
#define TOPK  8
#define PE    16

// ---------------------------------------------------------------------------
// Kernel 1: cosine distances. One wave (64 lanes) per (batch, token).
// grid = (196, 64), block = 256 (4 waves). 196*4 = 784 tokens.
// ---------------------------------------------------------------------------
__global__ __launch_bounds__(256) void dist_kernel(const float* __restrict__ x,
                                                   float* __restrict__ dist) {
    const int b    = blockIdx.y;
    const int wave = threadIdx.x >> 6;
    const int lane = threadIdx.x & 63;
    const int t    = blockIdx.x * 4 + wave;   // 0..783

    const float4* g = (const float4*)(x + (size_t)b * 785 * DIM);
    const float4* l = (const float4*)(x + (size_t)b * 785 * DIM + (size_t)(1 + t) * DIM);

    float dot = 0.f, l2 = 0.f, g2 = 0.f;
#pragma unroll
    for (int k = 0; k < 3; ++k) {
        float4 gv = g[lane + 64 * k];
        float4 lv = l[lane + 64 * k];
        dot += gv.x * lv.x + gv.y * lv.y + gv.z * lv.z + gv.w * lv.w;
        l2  += lv.x * lv.x + lv.y * lv.y + lv.z * lv.z + lv.w * lv.w;
        g2  += gv.x * gv.x + gv.y * gv.y + gv.z * gv.z + gv.w * gv.w;
    }
#pragma unroll
    for (int off = 32; off > 0; off >>= 1) {
        dot += __shfl_xor(dot, off);
        l2  += __shfl_xor(l2, off);
        g2  += __shfl_xor(g2, off);
    }
    if (lane == 0) {
        float gn = fmaxf(sqrtf(g2), 1e-8f);
        float ln = fmaxf(sqrtf(l2), 1e-8f);
        dist[b * TOK + t] = dot / (gn * ln);
    }
}

// ---------------------------------------------------------------------------
// Kernel 2: top-8 — single wave per batch, values register-resident.
// 8 rounds of butterfly argmax over the strict total order
// (value desc, index asc) — matches lax.top_k tie semantics.
// grid = 64, block = 64.
// ---------------------------------------------------------------------------
__global__ __launch_bounds__(64) void topk_kernel(const float* __restrict__ dist,
                                                  int4* __restrict__ boxes) {
    const int b    = blockIdx.x;
    const int lane = threadIdx.x;

    float v[13];
#pragma unroll
    for (int k = 0; k < 13; ++k) {
        int t = lane + 64 * k;
        v[k] = (t < TOK) ? dist[b * TOK + t] : -INFINITY;
    }

    int minx = 1 << 30, maxx = -1, miny = 1 << 30, maxy = -1;

    for (int iter = 0; iter < TOPK; ++iter) {
        // lane-local argmax; ascending k + strict '>' keeps lowest index on tie
        float best = -INFINITY;
        int   bk   = 0;
#pragma unroll
        for (int k = 0; k < 13; ++k) {
            if (v[k] > best) { best = v[k]; bk = k; }
        }
        int bidx = lane + 64 * bk;
        // wave-wide argmax (butterfly; consistent total order → all lanes agree)
#pragma unroll
        for (int off = 32; off > 0; off >>= 1) {
            float ov = __shfl_xor(best, off);
            int   oi = __shfl_xor(bidx, off);
            if (ov > best || (ov == best && oi < bidx)) { best = ov; bidx = oi; }
        }
        // owner lane knocks the winner out
        if ((bidx & 63) == lane) v[bidx >> 6] = -INFINITY;
        int ix = bidx / FH, iy = bidx % FH;
        minx = min(minx, ix); maxx = max(maxx, ix);
        miny = min(miny, iy); maxy = max(maxy, iy);
    }

    if (lane == 0) {
        int x_i = minx * PE, x_f = maxx * PE;
        int y_i = miny * PE, y_f = maxy * PE;
        int x0 = max(x_i, 0);
        int y0 = max(y_i, 0);
        int x1 = min(max(x_f, x_i + PE), IMG);
        int y1 = min(max(y_f, y_i + PE), IMG);
        boxes[b] = make_int4(x0, x1, y0, y1);
    }
}

// ---------------------------------------------------------------------------
// Kernel 3: bilinear crop-resize via LDS row staging.
// Block = 256 threads handles 4 output rows of one (b,c) plane.
// The <=5 source rows those 4 output rows touch are loaded full-width
// (coalesced float4) into LDS; bilinear gathers then hit LDS.
// row*(h-1) is exact in fp32 (< 2^24) so sy is monotone in row -> the
// block-uniform [rbase, rlast] bound is provably sufficient.
// grid = (112, 3, 64).
// ---------------------------------------------------------------------------
__global__ __launch_bounds__(256) void resize_kernel(const float* __restrict__ images,
                                                     const int4* __restrict__ boxes,
                                                     float* __restrict__ out) {
    const int b    = blockIdx.z;
    const int c    = blockIdx.y;
    const int r0   = blockIdx.x * 4;
    const int tid  = threadIdx.x;
    const int lane = tid & 63;
    const int rblk = tid >> 6;           // 0..3: output row within block

    const int4 box = boxes[b];
    const float x0f = (float)box.x;
    const int   x1  = box.y;
    const float y0f = (float)box.z;
    const int   y1  = box.w;
    const float h = (float)(x1 - box.x);
    const float w = (float)(y1 - box.z);
    const float scale = 1.0f / (float)(IMG - 1);

    // block-uniform source-row window
    const float sy0 = x0f + (float)r0 * (h - 1.0f) * scale;
    const float sy3 = x0f + (float)(r0 + 3) * (h - 1.0f) * scale;
    const int rbase = (int)floorf(sy0);
    int rlast = min((int)floorf(sy3) + 1, x1 - 1);
    int nrows = rlast - rbase + 1;
    nrows = max(1, min(nrows, 5));

    __shared__ float srows[5][IMG];

    const float* img = images + ((size_t)b * 3 + c) * (IMG * IMG);
    const int total = nrows * (IMG / 4);
    for (int i = tid; i < total; i += 256) {
        int r  = i / (IMG / 4);
        int c4 = i - r * (IMG / 4);
        float4 vv = *(const float4*)(img + (size_t)(rbase + r) * IMG + c4 * 4);
        *(float4*)&srows[r][c4 * 4] = vv;
    }
    __syncthreads();

    const int row = r0 + rblk;
    const float sy = x0f + (float)row * (h - 1.0f) * scale;
    int   y_lo = (int)floorf(sy);
    int   y_hi = min(y_lo + 1, x1 - 1);
    float wy   = sy - (float)y_lo;

    const float* rlo = srows[y_lo - rbase];
    const float* rhi = srows[y_hi - rbase];
    float* orow = out + (((size_t)b * 3 + c) * IMG + row) * IMG;

#pragma unroll
    for (int kk = 0; kk < 7; ++kk) {
        int j = lane + 64 * kk;          // lane-strided -> <=2-way LDS aliasing (free)
        float sx = y0f + (float)j * (w - 1.0f) * scale;
        int   x_lo = (int)floorf(sx);
        int   x_hi = min(x_lo + 1, y1 - 1);
        float wx   = sx - (float)x_lo;
        float a  = rlo[x_lo];
        float bb = rlo[x_hi];
        float cc = rhi[x_lo];
        float dd = rhi[x_hi];
        orow[j] = (1.f - wy) * ((1.f - wx) * a + wx * bb) +
                  wy * ((1.f - wx) * cc + wx * dd);
    }
}

// ---------------------------------------------------------------------------
extern "C" void kernel_launch(void* const* d_in, const int* in_sizes, int n_in,
                              void* d_out, int out_size, void* d_ws, size_t ws_size,
                              hipStream_t stream) {
    const float* x      = (const float*)d_in[0];
    const float* images = (const float*)d_in[1];
    float*       out    = (float*)d_out;

    float* dist  = (float*)d_ws;                                       // 64*784 floats
    int4*  boxes = (int4*)((char*)d_ws + BATCH * TOK * sizeof(float)); // 16B-aligned

    dist_kernel<<<dim3(TOK / 4, BATCH), 256, 0, stream>>>(x, dist);
    topk_kernel<<<BATCH, 64, 0, stream>>>(dist, boxes);
    resize_kernel<<<dim3(IMG / 4, 3, BATCH), 256, 0, stream>>>(images, boxes, out);
}

// Round 3
// 351.874 us; speedup vs baseline: 1.1955x; 1.0092x over previous
//
#include <hip/hip_runtime.h>
#include <math.h>

#define BATCH 64
#define TOK   784        // 785 - 1 local tokens
#define DIM   768
#define FH    28         // int(sqrt(785))
#define IMG   448
#define TOPK  8
#define PE    16

// ---------------------------------------------------------------------------
// Kernel 1: ranking scores. One wave (64 lanes) per (batch, token).
// NOTE: reference score = dot/(|g|*|l|). |g| is constant within a batch and
// the output depends only on the per-batch top-k RANKING, so we skip the
// division by |g| entirely (positive scale preserves order).
// grid = (196, 64), block = 256 (4 waves).
// ---------------------------------------------------------------------------
__global__ __launch_bounds__(256) void dist_kernel(const float* __restrict__ x,
                                                   float* __restrict__ dist) {
    const int b    = blockIdx.y;
    const int wave = threadIdx.x >> 6;
    const int lane = threadIdx.x & 63;
    const int t    = blockIdx.x * 4 + wave;   // 0..783

    const float4* g = (const float4*)(x + (size_t)b * 785 * DIM);
    const float4* l = (const float4*)(x + (size_t)b * 785 * DIM + (size_t)(1 + t) * DIM);

    float dot = 0.f, l2 = 0.f;
#pragma unroll
    for (int k = 0; k < 3; ++k) {
        float4 gv = g[lane + 64 * k];
        float4 lv = l[lane + 64 * k];
        dot += gv.x * lv.x + gv.y * lv.y + gv.z * lv.z + gv.w * lv.w;
        l2  += lv.x * lv.x + lv.y * lv.y + lv.z * lv.z + lv.w * lv.w;
    }
#pragma unroll
    for (int off = 32; off > 0; off >>= 1) {
        dot += __shfl_xor(dot, off);
        l2  += __shfl_xor(l2, off);
    }
    if (lane == 0) {
        float ln = fmaxf(sqrtf(l2), 1e-8f);
        dist[b * TOK + t] = dot / ln;
    }
}

// ---------------------------------------------------------------------------
// Kernel 2: top-8 — single wave per batch, values register-resident.
// 8 rounds of butterfly argmax over the strict total order
// (value desc, index asc) — matches lax.top_k tie semantics.
// grid = 64, block = 64.
// ---------------------------------------------------------------------------
__global__ __launch_bounds__(64) void topk_kernel(const float* __restrict__ dist,
                                                  int4* __restrict__ boxes) {
    const int b    = blockIdx.x;
    const int lane = threadIdx.x;

    float v[13];
#pragma unroll
    for (int k = 0; k < 13; ++k) {
        int t = lane + 64 * k;
        v[k] = (t < TOK) ? dist[b * TOK + t] : -INFINITY;
    }

    int minx = 1 << 30, maxx = -1, miny = 1 << 30, maxy = -1;

    for (int iter = 0; iter < TOPK; ++iter) {
        float best = -INFINITY;
        int   bk   = 0;
#pragma unroll
        for (int k = 0; k < 13; ++k) {
            if (v[k] > best) { best = v[k]; bk = k; }
        }
        int bidx = lane + 64 * bk;
#pragma unroll
        for (int off = 32; off > 0; off >>= 1) {
            float ov = __shfl_xor(best, off);
            int   oi = __shfl_xor(bidx, off);
            if (ov > best || (ov == best && oi < bidx)) { best = ov; bidx = oi; }
        }
        if ((bidx & 63) == lane) v[bidx >> 6] = -INFINITY;
        int ix = bidx / FH, iy = bidx % FH;
        minx = min(minx, ix); maxx = max(maxx, ix);
        miny = min(miny, iy); maxy = max(maxy, iy);
    }

    if (lane == 0) {
        int x_i = minx * PE, x_f = maxx * PE;
        int y_i = miny * PE, y_f = maxy * PE;
        int x0 = max(x_i, 0);
        int y0 = max(y_i, 0);
        int x1 = min(max(x_f, x_i + PE), IMG);
        int y1 = min(max(y_f, y_i + PE), IMG);
        boxes[b] = make_int4(x0, x1, y0, y1);
    }
}

// ---------------------------------------------------------------------------
// Kernel 3: bilinear crop-resize via LDS row staging, column-windowed.
// Block = 256 threads handles 4 output rows of one (b,c) plane.
// Only the needed column window [c0, c1e) of the <=5 source rows is staged
// (c0 = y0 rounded down to float4, c1e = y1 rounded up — all sampled columns
// lie in [y0, y1-1]).  grid = (112, 3, 64).
// ---------------------------------------------------------------------------
__global__ __launch_bounds__(256) void resize_kernel(const float* __restrict__ images,
                                                     const int4* __restrict__ boxes,
                                                     float* __restrict__ out) {
    const int b    = blockIdx.z;
    const int c    = blockIdx.y;
    const int r0   = blockIdx.x * 4;
    const int tid  = threadIdx.x;
    const int lane = tid & 63;
    const int rblk = tid >> 6;           // 0..3: output row within block

    const int4 box = boxes[b];
    const float x0f = (float)box.x;
    const int   x1  = box.y;
    const float y0f = (float)box.z;
    const int   y1  = box.w;
    const float h = (float)(x1 - box.x);
    const float w = (float)(y1 - box.z);
    const float scale = 1.0f / (float)(IMG - 1);

    // block-uniform source-row window (row*(h-1) exact in fp32 -> monotone)
    const float sy0 = x0f + (float)r0 * (h - 1.0f) * scale;
    const float sy3 = x0f + (float)(r0 + 3) * (h - 1.0f) * scale;
    const int rbase = (int)floorf(sy0);
    int rlast = min((int)floorf(sy3) + 1, x1 - 1);
    int nrows = rlast - rbase + 1;
    nrows = max(1, min(nrows, 5));

    // column window, float4-aligned
    const int c0   = box.z & ~3;
    const int c1e  = min(IMG, (y1 + 3) & ~3);
    const int nc4  = (c1e - c0) >> 2;    // float4s per staged row

    __shared__ float srows[5][IMG];

    const float* img = images + ((size_t)b * 3 + c) * (IMG * IMG);
    const int total = nrows * nc4;
    for (int i = tid; i < total; i += 256) {
        int r  = i / nc4;
        int c4 = i - r * nc4;
        float4 vv = *(const float4*)(img + (size_t)(rbase + r) * IMG + c0 + c4 * 4);
        *(float4*)&srows[r][c4 * 4] = vv;
    }
    __syncthreads();

    const int row = r0 + rblk;
    const float sy = x0f + (float)row * (h - 1.0f) * scale;
    int   y_lo = (int)floorf(sy);
    int   y_hi = min(y_lo + 1, x1 - 1);
    float wy   = sy - (float)y_lo;

    const float* rlo = srows[y_lo - rbase] - c0;   // index with global column
    const float* rhi = srows[y_hi - rbase] - c0;
    float* orow = out + (((size_t)b * 3 + c) * IMG + row) * IMG;

#pragma unroll
    for (int kk = 0; kk < 7; ++kk) {
        int j = lane + 64 * kk;          // lane-strided -> <=2-way LDS aliasing (free)
        float sx = y0f + (float)j * (w - 1.0f) * scale;
        int   x_lo = (int)floorf(sx);
        int   x_hi = min(x_lo + 1, y1 - 1);
        float wx   = sx - (float)x_lo;
        float a  = rlo[x_lo];
        float bb = rlo[x_hi];
        float cc = rhi[x_lo];
        float dd = rhi[x_hi];
        orow[j] = (1.f - wy) * ((1.f - wx) * a + wx * bb) +
                  wy * ((1.f - wx) * cc + wx * dd);
    }
}

// ---------------------------------------------------------------------------
extern "C" void kernel_launch(void* const* d_in, const int* in_sizes, int n_in,
                              void* d_out, int out_size, void* d_ws, size_t ws_size,
                              hipStream_t stream) {
    const float* x      = (const float*)d_in[0];
    const float* images = (const float*)d_in[1];
    float*       out    = (float*)d_out;

    float* dist  = (float*)d_ws;                                       // 64*784 floats
    int4*  boxes = (int4*)((char*)d_ws + BATCH * TOK * sizeof(float)); // 16B-aligned

    dist_kernel<<<dim3(TOK / 4, BATCH), 256, 0, stream>>>(x, dist);
    topk_kernel<<<BATCH, 64, 0, stream>>>(dist, boxes);
    resize_kernel<<<dim3(IMG / 4, 3, BATCH), 256, 0, stream>>>(images, boxes, out);
}